// Round 1
// baseline (1806.183 us; speedup 1.0000x reference)
//
#include <hip/hip_runtime.h>
#include <math.h>

#define HW 9216   // 96*96

// ------------------------------------------------------------------
// k1: 1x1 conv. Gto[o][p] = sum_c w[o][c]*x[c, pixel] + b[o],
//     stored with permuted pixel index p = w*96 + h  (o-major).
// ------------------------------------------------------------------
__global__ __launch_bounds__(256) void k1_conv(
        const float* __restrict__ x, const float* __restrict__ wc,
        const float* __restrict__ bc, float* __restrict__ Gto) {
    __shared__ float wt[256][32];          // wt[c][o]
    int t = threadIdx.x;
    for (int i = t; i < 256 * 32; i += 256) {
        int o = i >> 8, c = i & 255;       // wc is [o][c]
        wt[c][o] = wc[i];
    }
    __syncthreads();
    int n = blockIdx.x * 256 + t;          // natural pixel index h*96+w
    float acc[32];
    #pragma unroll
    for (int o = 0; o < 32; ++o) acc[o] = bc[o];
    for (int c = 0; c < 256; ++c) {
        float xv = x[c * HW + n];
        #pragma unroll
        for (int o4 = 0; o4 < 8; ++o4) {
            float4 wv = *(const float4*)&wt[c][o4 * 4];
            acc[o4*4+0] = fmaf(wv.x, xv, acc[o4*4+0]);
            acc[o4*4+1] = fmaf(wv.y, xv, acc[o4*4+1]);
            acc[o4*4+2] = fmaf(wv.z, xv, acc[o4*4+2]);
            acc[o4*4+3] = fmaf(wv.w, xv, acc[o4*4+3]);
        }
    }
    int h = n / 96, w = n % 96;
    int p = w * 96 + h;
    #pragma unroll
    for (int o = 0; o < 32; ++o) Gto[o * HW + p] = acc[o];
}

// ------------------------------------------------------------------
// k2: per-row online softmax stats of S = G^T G.
// Block = 64 rows x one q-half (4608). 288 blocks. Register tile 4j x 8q.
// ------------------------------------------------------------------
__global__ __launch_bounds__(256) void k2_stats(
        const float* __restrict__ Gto, float* __restrict__ m_part,
        float* __restrict__ l_part) {
    __shared__ float Gj[32][64];
    __shared__ float Gq[32][128];
    int t = threadIdx.x;
    int jb = blockIdx.x % 144, half = blockIdx.x / 144;
    int j0 = jb * 64;
    {   // stage Gj (o-major row tile), 2048 floats
        int flat = t * 8, o = flat >> 6, c0 = flat & 63;
        *(float4*)&Gj[o][c0]     = *(const float4*)&Gto[o * HW + j0 + c0];
        *(float4*)&Gj[o][c0 + 4] = *(const float4*)&Gto[o * HW + j0 + c0 + 4];
    }
    int ty = t >> 4, tx = t & 15;          // rows j0+ty*4+i, q cols tx*8+j
    float m[4], l[4];
    #pragma unroll
    for (int i = 0; i < 4; ++i) { m[i] = -INFINITY; l[i] = 0.f; }
    int qbeg = half * (HW / 2);
    for (int qt = 0; qt < HW / 2; qt += 128) {
        __syncthreads();
        {   // stage Gq tile, 4096 floats
            int flat = t * 16, o = flat >> 7, c0 = flat & 127;
            #pragma unroll
            for (int k = 0; k < 4; ++k)
                *(float4*)&Gq[o][c0 + 4*k] =
                    *(const float4*)&Gto[o * HW + qbeg + qt + c0 + 4*k];
        }
        __syncthreads();
        float acc[4][8];
        #pragma unroll
        for (int i = 0; i < 4; ++i)
            #pragma unroll
            for (int j = 0; j < 8; ++j) acc[i][j] = 0.f;
        #pragma unroll 8
        for (int o = 0; o < 32; ++o) {
            float4 a  = *(const float4*)&Gj[o][ty * 4];
            float4 b0 = *(const float4*)&Gq[o][tx * 8];
            float4 b1 = *(const float4*)&Gq[o][tx * 8 + 4];
            float av[4] = {a.x, a.y, a.z, a.w};
            float bv[8] = {b0.x, b0.y, b0.z, b0.w, b1.x, b1.y, b1.z, b1.w};
            #pragma unroll
            for (int i = 0; i < 4; ++i)
                #pragma unroll
                for (int j = 0; j < 8; ++j)
                    acc[i][j] = fmaf(av[i], bv[j], acc[i][j]);
        }
        #pragma unroll
        for (int i = 0; i < 4; ++i) {
            float tm = acc[i][0];
            #pragma unroll
            for (int j = 1; j < 8; ++j) tm = fmaxf(tm, acc[i][j]);
            float nm = fmaxf(m[i], tm);
            float s = 0.f;
            #pragma unroll
            for (int j = 0; j < 8; ++j) s += __expf(acc[i][j] - nm);
            l[i] = l[i] * __expf(m[i] - nm) + s;   // expf(-inf)=0 first tile
            m[i] = nm;
        }
    }
    // merge across the 16 tx lanes sharing the same rows (within-wave)
    #pragma unroll
    for (int off = 1; off < 16; off <<= 1) {
        #pragma unroll
        for (int i = 0; i < 4; ++i) {
            float mo = __shfl_xor(m[i], off);
            float lo = __shfl_xor(l[i], off);
            float nm = fmaxf(m[i], mo);
            l[i] = l[i] * __expf(m[i] - nm) + lo * __expf(mo - nm);
            m[i] = nm;
        }
    }
    if (tx == 0) {
        #pragma unroll
        for (int i = 0; i < 4; ++i) {
            int j = j0 + ty * 4 + i;
            m_part[half * HW + j] = m[i];
            l_part[half * HW + j] = l[i];
        }
    }
}

// merge the two q-halves -> final m, 1/l
__global__ __launch_bounds__(256) void k2b_merge(
        const float* __restrict__ m_part, const float* __restrict__ l_part,
        float* __restrict__ mg, float* __restrict__ rlg) {
    int j = blockIdx.x * 256 + threadIdx.x;
    float m0 = m_part[j], m1 = m_part[HW + j];
    float l0 = l_part[j], l1 = l_part[HW + j];
    float nm = fmaxf(m0, m1);
    float l  = l0 * __expf(m0 - nm) + l1 * __expf(m1 - nm);
    mg[j]  = nm;
    rlg[j] = 1.0f / l;
}

// ------------------------------------------------------------------
// k3: fused Z[c,q] = sum_j x[c,j] * exp(S[j,q]-m_j)/l_j.
// Block owns 32 q-cols x all 256 c. Per p-tile(32): phase A recomputes
// S-tile + exp into LDS, phase B rank-32 update with 8c x 4q reg tile.
// ------------------------------------------------------------------
__global__ __launch_bounds__(256) void k3_pv(
        const float* __restrict__ x, const float* __restrict__ Gto,
        const float* __restrict__ mg, const float* __restrict__ rlg,
        float* __restrict__ Z) {
    __shared__ float Gq[32][32];
    __shared__ float Gp[32][32];
    __shared__ float P[32][36];
    __shared__ float xc[256][33];          // pad 33: bank = (tc+p)%32, clean
    int t = threadIdx.x;
    int q0 = blockIdx.x * 32;
    {   // stage Gq once (loop-invariant)
        int o = t >> 3, c0 = (t & 7) * 4;
        *(float4*)&Gq[o][c0] = *(const float4*)&Gto[o * HW + q0 + c0];
    }
    int tc = t & 31, tq = t >> 5;          // c = tc+32i, q = q0+tq*4+j
    int pa = t >> 3, qa = (t & 7) * 4;     // phase-A: one p-row, 4 q
    float4 acc[8];
    #pragma unroll
    for (int i = 0; i < 8; ++i) acc[i] = make_float4(0.f, 0.f, 0.f, 0.f);

    for (int p0 = 0; p0 < HW; p0 += 32) {
        __syncthreads();                   // prev phase-B done with xc/P
        {   // stage Gp tile
            int o = t >> 3, c0 = (t & 7) * 4;
            *(float4*)&Gp[o][c0] = *(const float4*)&Gto[o * HW + p0 + c0];
        }
        {   // stage xc: thread t = row c, 32 floats along p
            const float* src = &x[t * HW + p0];
            #pragma unroll
            for (int k = 0; k < 8; ++k) {
                float4 v = *(const float4*)&src[4 * k];
                xc[t][4*k+0] = v.x; xc[t][4*k+1] = v.y;
                xc[t][4*k+2] = v.z; xc[t][4*k+3] = v.w;
            }
        }
        __syncthreads();
        // phase A: S[pa][qa..qa+3] = dot32(Gto[:,p0+pa], Gto[:,q0+qa..])
        float s0 = 0.f, s1 = 0.f, s2 = 0.f, s3 = 0.f;
        #pragma unroll 8
        for (int o = 0; o < 32; ++o) {
            float  av = Gp[o][pa];
            float4 bv = *(const float4*)&Gq[o][qa];
            s0 = fmaf(av, bv.x, s0); s1 = fmaf(av, bv.y, s1);
            s2 = fmaf(av, bv.z, s2); s3 = fmaf(av, bv.w, s3);
        }
        float mp = mg[p0 + pa], rl = rlg[p0 + pa];
        float4 pv;
        pv.x = __expf(s0 - mp) * rl; pv.y = __expf(s1 - mp) * rl;
        pv.z = __expf(s2 - mp) * rl; pv.w = __expf(s3 - mp) * rl;
        *(float4*)&P[pa][qa] = pv;
        __syncthreads();
        // phase B: rank-32 update
        #pragma unroll 4
        for (int p = 0; p < 32; ++p) {
            float4 b = *(const float4*)&P[p][tq * 4];
            float a[8];
            #pragma unroll
            for (int i = 0; i < 8; ++i) a[i] = xc[tc + 32 * i][p];
            #pragma unroll
            for (int i = 0; i < 8; ++i) {
                acc[i].x = fmaf(a[i], b.x, acc[i].x);
                acc[i].y = fmaf(a[i], b.y, acc[i].y);
                acc[i].z = fmaf(a[i], b.z, acc[i].z);
                acc[i].w = fmaf(a[i], b.w, acc[i].w);
            }
        }
    }
    #pragma unroll
    for (int i = 0; i < 8; ++i)
        *(float4*)&Z[(tc + 32 * i) * HW + q0 + tq * 4] = acc[i];
}

// ------------------------------------------------------------------
// k4: per-c row softmax of Z (len 9216) fused with final softmax over W.
// Z lives in d_out; row fully staged to LDS before overwrite -> safe.
// ------------------------------------------------------------------
__global__ __launch_bounds__(256) void k4_softmax(
        const float* __restrict__ x, float* __restrict__ ZO) {
    __shared__ float zrow[HW];
    __shared__ float red[4];
    int t = threadIdx.x, c = blockIdx.x;
    int lane = t & 63, wid = t >> 6;
    const float* Zr = &ZO[c * HW];
    float lm = -INFINITY;
    #pragma unroll
    for (int k = 0; k < 36; ++k) {
        float v = Zr[t + 256 * k];
        zrow[t + 256 * k] = v;
        lm = fmaxf(lm, v);
    }
    #pragma unroll
    for (int off = 32; off; off >>= 1) lm = fmaxf(lm, __shfl_xor(lm, off));
    if (lane == 0) red[wid] = lm;
    __syncthreads();
    float M = fmaxf(fmaxf(red[0], red[1]), fmaxf(red[2], red[3]));
    __syncthreads();
    float ls = 0.f;
    #pragma unroll
    for (int k = 0; k < 36; ++k) {
        int i = t + 256 * k;
        float e = __expf(zrow[i] - M);
        zrow[i] = e;
        ls += e;
    }
    #pragma unroll
    for (int off = 32; off; off >>= 1) ls += __shfl_xor(ls, off);
    if (lane == 0) red[wid] = ls;
    __syncthreads();
    float rS = 1.0f / (red[0] + red[1] + red[2] + red[3]);
    const float* xr = &x[c * HW];
    float* outr = &ZO[c * HW];
    // 96 sub-rows of length 96; wave wid handles h = wid + 4*kk
    for (int kk = 0; kk < 24; ++kk) {
        int h = wid + kk * 4;
        int base = h * 96;
        float v0 = fmaf(zrow[base + lane], rS, xr[base + lane]);
        float v1 = (lane < 32)
                 ? fmaf(zrow[base + 64 + lane], rS, xr[base + 64 + lane])
                 : -INFINITY;
        float mm = fmaxf(v0, v1);
        #pragma unroll
        for (int off = 32; off; off >>= 1) mm = fmaxf(mm, __shfl_xor(mm, off));
        float e0 = __expf(v0 - mm);
        float e1 = (lane < 32) ? __expf(v1 - mm) : 0.f;
        float ss = e0 + e1;
        #pragma unroll
        for (int off = 32; off; off >>= 1) ss += __shfl_xor(ss, off);
        float r = 1.0f / ss;
        outr[base + lane] = e0 * r;
        if (lane < 32) outr[base + 64 + lane] = e1 * r;
    }
}

extern "C" void kernel_launch(void* const* d_in, const int* in_sizes, int n_in,
                              void* d_out, int out_size, void* d_ws, size_t ws_size,
                              hipStream_t stream) {
    const float* x  = (const float*)d_in[0];   // [256,96,96]
    const float* wc = (const float*)d_in[1];   // [32,256]
    const float* bc = (const float*)d_in[2];   // [32]
    float* Z = (float*)d_out;                  // reused: Z then final out

    float* Gto    = (float*)d_ws;              // 32*9216
    float* m_part = Gto + 32 * HW;             // 2*9216
    float* l_part = m_part + 2 * HW;           // 2*9216
    float* mg     = l_part + 2 * HW;           // 9216
    float* rlg    = mg + HW;                   // 9216   (total ~1.4 MB)

    k1_conv   <<<36,  256, 0, stream>>>(x, wc, bc, Gto);
    k2_stats  <<<288, 256, 0, stream>>>(Gto, m_part, l_part);
    k2b_merge <<<36,  256, 0, stream>>>(m_part, l_part, mg, rlg);
    k3_pv     <<<288, 256, 0, stream>>>(x, Gto, mg, rlg, Z);
    k4_softmax<<<256, 256, 0, stream>>>(x, Z);
}

// Round 2
// 403.728 us; speedup vs baseline: 4.4738x; 4.4738x over previous
//
#include <hip/hip_runtime.h>
#include <math.h>

#define HW 9216   // 96*96

typedef __attribute__((ext_vector_type(8))) short bf16x8;
typedef __attribute__((ext_vector_type(4))) float f32x4;
typedef unsigned short ushort_t;
typedef unsigned int uint_t;

__device__ __forceinline__ ushort_t f2bf(float f) {
    union { float f; uint_t u; } v; v.f = f;
    uint_t u = v.u + 0x7FFF + ((v.u >> 16) & 1);   // RNE
    return (ushort_t)(u >> 16);
}

// ------------------------------------------------------------------
// k1: 1x1 conv. Writes:
//   Gto[o][p]  f32   (p = w*96+h permuted)   -- for k2 stats
//   Gbt[p][o]  bf16  (row-major, o contig)   -- MFMA A / B^T frags
//   xbf[c][n]  bf16                          -- PV A operand source
// ------------------------------------------------------------------
__global__ __launch_bounds__(256) void k1_conv(
        const float* __restrict__ x, const float* __restrict__ wc,
        const float* __restrict__ bc, float* __restrict__ Gto,
        ushort_t* __restrict__ Gbt, ushort_t* __restrict__ xbf) {
    __shared__ float wt[256][32];          // wt[c][o]
    int t = threadIdx.x;
    for (int i = t; i < 256 * 32; i += 256) {
        int o = i >> 8, c = i & 255;       // wc is [o][c]
        wt[c][o] = wc[i];
    }
    __syncthreads();
    int n = blockIdx.x * 256 + t;          // natural pixel index h*96+w
    float acc[32];
    #pragma unroll
    for (int o = 0; o < 32; ++o) acc[o] = bc[o];
    for (int c = 0; c < 256; ++c) {
        float xv = x[c * HW + n];
        xbf[c * HW + n] = f2bf(xv);
        #pragma unroll
        for (int o4 = 0; o4 < 8; ++o4) {
            float4 wv = *(const float4*)&wt[c][o4 * 4];
            acc[o4*4+0] = fmaf(wv.x, xv, acc[o4*4+0]);
            acc[o4*4+1] = fmaf(wv.y, xv, acc[o4*4+1]);
            acc[o4*4+2] = fmaf(wv.z, xv, acc[o4*4+2]);
            acc[o4*4+3] = fmaf(wv.w, xv, acc[o4*4+3]);
        }
    }
    int h = n / 96, w = n % 96;
    int p = w * 96 + h;
    #pragma unroll
    for (int o = 0; o < 32; ++o) {
        Gto[o * HW + p] = acc[o];
        Gbt[p * 32 + o] = f2bf(acc[o]);
    }
}

// ------------------------------------------------------------------
// k2: per-row online softmax stats of S = G^T G (fp32, unchanged).
// ------------------------------------------------------------------
__global__ __launch_bounds__(256) void k2_stats(
        const float* __restrict__ Gto, float* __restrict__ m_part,
        float* __restrict__ l_part) {
    __shared__ float Gj[32][64];
    __shared__ float Gq[32][128];
    int t = threadIdx.x;
    int jb = blockIdx.x % 144, half = blockIdx.x / 144;
    int j0 = jb * 64;
    {
        int flat = t * 8, o = flat >> 6, c0 = flat & 63;
        *(float4*)&Gj[o][c0]     = *(const float4*)&Gto[o * HW + j0 + c0];
        *(float4*)&Gj[o][c0 + 4] = *(const float4*)&Gto[o * HW + j0 + c0 + 4];
    }
    int ty = t >> 4, tx = t & 15;
    float m[4], l[4];
    #pragma unroll
    for (int i = 0; i < 4; ++i) { m[i] = -INFINITY; l[i] = 0.f; }
    int qbeg = half * (HW / 2);
    for (int qt = 0; qt < HW / 2; qt += 128) {
        __syncthreads();
        {
            int flat = t * 16, o = flat >> 7, c0 = flat & 127;
            #pragma unroll
            for (int k = 0; k < 4; ++k)
                *(float4*)&Gq[o][c0 + 4*k] =
                    *(const float4*)&Gto[o * HW + qbeg + qt + c0 + 4*k];
        }
        __syncthreads();
        float acc[4][8];
        #pragma unroll
        for (int i = 0; i < 4; ++i)
            #pragma unroll
            for (int j = 0; j < 8; ++j) acc[i][j] = 0.f;
        #pragma unroll 8
        for (int o = 0; o < 32; ++o) {
            float4 a  = *(const float4*)&Gj[o][ty * 4];
            float4 b0 = *(const float4*)&Gq[o][tx * 8];
            float4 b1 = *(const float4*)&Gq[o][tx * 8 + 4];
            float av[4] = {a.x, a.y, a.z, a.w};
            float bv[8] = {b0.x, b0.y, b0.z, b0.w, b1.x, b1.y, b1.z, b1.w};
            #pragma unroll
            for (int i = 0; i < 4; ++i)
                #pragma unroll
                for (int j = 0; j < 8; ++j)
                    acc[i][j] = fmaf(av[i], bv[j], acc[i][j]);
        }
        #pragma unroll
        for (int i = 0; i < 4; ++i) {
            float tm = acc[i][0];
            #pragma unroll
            for (int j = 1; j < 8; ++j) tm = fmaxf(tm, acc[i][j]);
            float nm = fmaxf(m[i], tm);
            float s = 0.f;
            #pragma unroll
            for (int j = 0; j < 8; ++j) s += __expf(acc[i][j] - nm);
            l[i] = l[i] * __expf(m[i] - nm) + s;
            m[i] = nm;
        }
    }
    #pragma unroll
    for (int off = 1; off < 16; off <<= 1) {
        #pragma unroll
        for (int i = 0; i < 4; ++i) {
            float mo = __shfl_xor(m[i], off);
            float lo = __shfl_xor(l[i], off);
            float nm = fmaxf(m[i], mo);
            l[i] = l[i] * __expf(m[i] - nm) + lo * __expf(mo - nm);
            m[i] = nm;
        }
    }
    if (tx == 0) {
        #pragma unroll
        for (int i = 0; i < 4; ++i) {
            int j = j0 + ty * 4 + i;
            m_part[half * HW + j] = m[i];
            l_part[half * HW + j] = l[i];
        }
    }
}

__global__ __launch_bounds__(256) void k2b_merge(
        const float* __restrict__ m_part, const float* __restrict__ l_part,
        float* __restrict__ mg, float* __restrict__ rlg) {
    int j = blockIdx.x * 256 + threadIdx.x;
    float m0 = m_part[j], m1 = m_part[HW + j];
    float l0 = l_part[j], l1 = l_part[HW + j];
    float nm = fmaxf(m0, m1);
    float l  = l0 * __expf(m0 - nm) + l1 * __expf(m1 - nm);
    mg[j]  = nm;
    rlg[j] = 1.0f / l;
}

// zero d_out before atomic accumulation
__global__ __launch_bounds__(256) void kzero(float* __restrict__ Z) {
    int i = blockIdx.x * 256 + threadIdx.x;
    *(float4*)&Z[i * 4] = make_float4(0.f, 0.f, 0.f, 0.f);
}

// ------------------------------------------------------------------
// k3: fused Z[c,q] += sum_{p in range} xbf[c,p] * exp(S[p,q]-m_p)/l_p
// via bf16 MFMA. Grid = 288 q-tiles x 4 p-splits = 1152 blocks,
// 512 threads (8 waves). Per 32-p tile:
//   phase A (waves 0-3): 1 MFMA S quadrant from Gbt (global, L2-hot),
//                        exp * 1/l -> Pbt[q][p] bf16 (LDS)
//   phase B (all waves): 4 MFMA, A = xb[c][p] (LDS), B = Pbt.
// Output: atomicAdd f32 into pre-zeroed Z.
// ------------------------------------------------------------------
__global__ __launch_bounds__(512) void k3_pv(
        const ushort_t* __restrict__ xbf, const ushort_t* __restrict__ Gbt,
        const float* __restrict__ mg, const float* __restrict__ rlg,
        float* __restrict__ Z) {
    __shared__ ushort_t xb[256][40];     // pad 40: 80B rows, 2-way banks, 16B aligned
    __shared__ ushort_t Pbt[32][40];     // [q][p] bf16
    int t = threadIdx.x;
    int w = t >> 6, l = t & 63;
    int l15 = l & 15, lg = l >> 4;       // frag row/col, k-group
    int qb = blockIdx.x % 288, ps = blockIdx.x / 288;
    int q0 = qb * 32;
    int p0beg = ps * 2304;               // 72 tiles of 32

    // phase-A B-fragment (G^T cols q, k=o contiguous) held in regs
    bf16x8 bqA = {};
    int pf = w >> 1, qf = w & 1;
    if (w < 4)
        bqA = *(const bf16x8*)&Gbt[(q0 + qf * 16 + l15) * 32 + lg * 8];

    f32x4 acc00 = {0.f,0.f,0.f,0.f}, acc01 = {0.f,0.f,0.f,0.f};
    f32x4 acc10 = {0.f,0.f,0.f,0.f}, acc11 = {0.f,0.f,0.f,0.f};

    int cstage = t >> 1, hf = t & 1;     // xb staging assignment

    for (int pt = 0; pt < 72; ++pt) {
        int p0 = p0beg + pt * 32;
        __syncthreads();                 // prior phase B done with xb/Pbt
        {   // stage xb: 256 c-rows x 32 p, bf16 (16 elems / thread)
            const ushort_t* src = &xbf[cstage * HW + p0 + hf * 16];
            uint4 v0 = *(const uint4*)src;
            uint4 v1 = *(const uint4*)(src + 8);
            *(uint4*)&xb[cstage][hf * 16]     = v0;
            *(uint4*)&xb[cstage][hf * 16 + 8] = v1;
        }
        if (w < 4) {   // phase A: one 16x16 S quadrant per wave
            bf16x8 ap = *(const bf16x8*)&Gbt[(p0 + pf * 16 + l15) * 32 + lg * 8];
            f32x4 s = {0.f,0.f,0.f,0.f};
            s = __builtin_amdgcn_mfma_f32_16x16x32_bf16(ap, bqA, s, 0, 0, 0);
            // C layout: row p = pf*16 + lg*4 + r, col q = qf*16 + l15
            int prow = p0 + pf * 16 + lg * 4;
            ushort_t pb0 = f2bf(__expf(s[0] - mg[prow + 0]) * rlg[prow + 0]);
            ushort_t pb1 = f2bf(__expf(s[1] - mg[prow + 1]) * rlg[prow + 1]);
            ushort_t pb2 = f2bf(__expf(s[2] - mg[prow + 2]) * rlg[prow + 2]);
            ushort_t pb3 = f2bf(__expf(s[3] - mg[prow + 3]) * rlg[prow + 3]);
            uint2 pk;
            pk.x = (uint_t)pb0 | ((uint_t)pb1 << 16);
            pk.y = (uint_t)pb2 | ((uint_t)pb3 << 16);
            *(uint2*)&Pbt[qf * 16 + l15][pf * 16 + lg * 4] = pk;
        }
        __syncthreads();                 // xb + Pbt ready
        // phase B: Z-tile [64c x 32q] per wave, k = 32
        bf16x8 b0 = *(const bf16x8*)&Pbt[l15][lg * 8];
        bf16x8 b1 = *(const bf16x8*)&Pbt[16 + l15][lg * 8];
        bf16x8 a0 = *(const bf16x8*)&xb[w * 32 + l15][lg * 8];
        bf16x8 a1 = *(const bf16x8*)&xb[w * 32 + 16 + l15][lg * 8];
        acc00 = __builtin_amdgcn_mfma_f32_16x16x32_bf16(a0, b0, acc00, 0, 0, 0);
        acc01 = __builtin_amdgcn_mfma_f32_16x16x32_bf16(a0, b1, acc01, 0, 0, 0);
        acc10 = __builtin_amdgcn_mfma_f32_16x16x32_bf16(a1, b0, acc10, 0, 0, 0);
        acc11 = __builtin_amdgcn_mfma_f32_16x16x32_bf16(a1, b1, acc11, 0, 0, 0);
    }
    // writeback: c = w*32 + cf*16 + lg*4 + r, q = q0 + qf*16 + l15
    int cbase = w * 32 + lg * 4;
    int qcol  = q0 + l15;
    #pragma unroll
    for (int r = 0; r < 4; ++r) {
        atomicAdd(&Z[(cbase + r)      * HW + qcol],      acc00[r]);
        atomicAdd(&Z[(cbase + r)      * HW + qcol + 16], acc01[r]);
        atomicAdd(&Z[(cbase + 16 + r) * HW + qcol],      acc10[r]);
        atomicAdd(&Z[(cbase + 16 + r) * HW + qcol + 16], acc11[r]);
    }
}

// ------------------------------------------------------------------
// k4: per-c row softmax of Z (len 9216) fused with final softmax over W.
// ------------------------------------------------------------------
__global__ __launch_bounds__(256) void k4_softmax(
        const float* __restrict__ x, float* __restrict__ ZO) {
    __shared__ float zrow[HW];
    __shared__ float red[4];
    int t = threadIdx.x, c = blockIdx.x;
    int lane = t & 63, wid = t >> 6;
    const float* Zr = &ZO[c * HW];
    float lm = -INFINITY;
    #pragma unroll
    for (int k = 0; k < 36; ++k) {
        float v = Zr[t + 256 * k];
        zrow[t + 256 * k] = v;
        lm = fmaxf(lm, v);
    }
    #pragma unroll
    for (int off = 32; off; off >>= 1) lm = fmaxf(lm, __shfl_xor(lm, off));
    if (lane == 0) red[wid] = lm;
    __syncthreads();
    float M = fmaxf(fmaxf(red[0], red[1]), fmaxf(red[2], red[3]));
    __syncthreads();
    float ls = 0.f;
    #pragma unroll
    for (int k = 0; k < 36; ++k) {
        int i = t + 256 * k;
        float e = __expf(zrow[i] - M);
        zrow[i] = e;
        ls += e;
    }
    #pragma unroll
    for (int off = 32; off; off >>= 1) ls += __shfl_xor(ls, off);
    if (lane == 0) red[wid] = ls;
    __syncthreads();
    float rS = 1.0f / (red[0] + red[1] + red[2] + red[3]);
    const float* xr = &x[c * HW];
    float* outr = &ZO[c * HW];
    for (int kk = 0; kk < 24; ++kk) {
        int h = wid + kk * 4;
        int base = h * 96;
        float v0 = fmaf(zrow[base + lane], rS, xr[base + lane]);
        float v1 = (lane < 32)
                 ? fmaf(zrow[base + 64 + lane], rS, xr[base + 64 + lane])
                 : -INFINITY;
        float mm = fmaxf(v0, v1);
        #pragma unroll
        for (int off = 32; off; off >>= 1) mm = fmaxf(mm, __shfl_xor(mm, off));
        float e0 = __expf(v0 - mm);
        float e1 = (lane < 32) ? __expf(v1 - mm) : 0.f;
        float ss = e0 + e1;
        #pragma unroll
        for (int off = 32; off; off >>= 1) ss += __shfl_xor(ss, off);
        float r = 1.0f / ss;
        outr[base + lane] = e0 * r;
        if (lane < 32) outr[base + 64 + lane] = e1 * r;
    }
}

extern "C" void kernel_launch(void* const* d_in, const int* in_sizes, int n_in,
                              void* d_out, int out_size, void* d_ws, size_t ws_size,
                              hipStream_t stream) {
    const float* x  = (const float*)d_in[0];   // [256,96,96]
    const float* wc = (const float*)d_in[1];   // [32,256]
    const float* bc = (const float*)d_in[2];   // [32]
    float* Z = (float*)d_out;                  // accum Z, then final out

    float* Gto    = (float*)d_ws;              // 32*9216 f32
    float* m_part = Gto + 32 * HW;             // 2*9216
    float* l_part = m_part + 2 * HW;           // 2*9216
    float* mg     = l_part + 2 * HW;           // 9216
    float* rlg    = mg + HW;                   // 9216
    ushort_t* xbf = (ushort_t*)(rlg + HW);     // 256*9216 bf16 (4.7MB)
    ushort_t* Gbt = xbf + 256 * HW;            // 9216*32 bf16 (590KB)

    k1_conv   <<<36,   256, 0, stream>>>(x, wc, bc, Gto, Gbt, xbf);
    k2_stats  <<<288,  256, 0, stream>>>(Gto, m_part, l_part);
    k2b_merge <<<36,   256, 0, stream>>>(m_part, l_part, mg, rlg);
    kzero     <<<2304, 256, 0, stream>>>(Z);
    k3_pv     <<<1152, 512, 0, stream>>>(xbf, Gbt, mg, rlg, Z);
    k4_softmax<<<256,  256, 0, stream>>>(x, Z);
}

// Round 3
// 233.202 us; speedup vs baseline: 7.7451x; 1.7312x over previous
//
#include <hip/hip_runtime.h>
#include <math.h>

#define HW 9216   // 96*96

typedef __attribute__((ext_vector_type(8))) short bf16x8;
typedef __attribute__((ext_vector_type(4))) float f32x4;
typedef unsigned short ushort_t;
typedef unsigned int uint_t;

__device__ __forceinline__ ushort_t f2bf(float f) {
    union { float f; uint_t u; } v; v.f = f;
    uint_t u = v.u + 0x7FFF + ((v.u >> 16) & 1);   // RNE
    return (ushort_t)(u >> 16);
}

// ------------------------------------------------------------------
// k1: 1x1 conv -> Gbt[p][o] bf16 (p = w*96+h permuted, o contiguous).
// 288 blocks x 256 threads: 32 pixels x 8 c-groups, LDS reduction.
// ------------------------------------------------------------------
__global__ __launch_bounds__(256) void k1_conv(
        const float* __restrict__ x, const float* __restrict__ wc,
        const float* __restrict__ bc, ushort_t* __restrict__ Gbt) {
    __shared__ float wt[256][32];          // [c][o] 32KB
    __shared__ float red[8][32][33];       // [cg][px][o] padded
    int t = threadIdx.x;
    for (int i = t; i < 256 * 32; i += 256) {
        int o = i >> 8, c = i & 255;       // wc is [o][c]
        wt[c][o] = wc[i];
    }
    __syncthreads();
    int px = t & 31, cg = t >> 5;
    int n = blockIdx.x * 32 + px;
    float acc[32];
    #pragma unroll
    for (int o = 0; o < 32; ++o) acc[o] = 0.f;
    int c0 = cg * 32;
    for (int cc = 0; cc < 32; ++cc) {
        int c = c0 + cc;
        float xv = x[c * HW + n];
        #pragma unroll
        for (int o4 = 0; o4 < 8; ++o4) {
            float4 wv = *(const float4*)&wt[c][o4 * 4];
            acc[o4*4+0] = fmaf(wv.x, xv, acc[o4*4+0]);
            acc[o4*4+1] = fmaf(wv.y, xv, acc[o4*4+1]);
            acc[o4*4+2] = fmaf(wv.z, xv, acc[o4*4+2]);
            acc[o4*4+3] = fmaf(wv.w, xv, acc[o4*4+3]);
        }
    }
    #pragma unroll
    for (int o = 0; o < 32; ++o) red[cg][px][o] = acc[o];
    __syncthreads();
    // 256 threads x 4 outputs: px2 = t>>3, o2 = (t&7)*4
    int px2 = t >> 3, o2 = (t & 7) * 4;
    float s[4] = {0.f, 0.f, 0.f, 0.f};
    #pragma unroll
    for (int g = 0; g < 8; ++g) {
        s[0] += red[g][px2][o2 + 0];
        s[1] += red[g][px2][o2 + 1];
        s[2] += red[g][px2][o2 + 2];
        s[3] += red[g][px2][o2 + 3];
    }
    int n2 = blockIdx.x * 32 + px2;
    int h = n2 / 96, w = n2 % 96;
    int p = w * 96 + h;
    uint2 pk;
    pk.x = (uint_t)f2bf(s[0] + bc[o2+0]) | ((uint_t)f2bf(s[1] + bc[o2+1]) << 16);
    pk.y = (uint_t)f2bf(s[2] + bc[o2+2]) | ((uint_t)f2bf(s[3] + bc[o2+3]) << 16);
    *(uint2*)&Gbt[p * 32 + o2] = pk;
}

// x (f32) -> xbf (bf16), vectorized
__global__ __launch_bounds__(256) void k1b_cvt(
        const float* __restrict__ x, ushort_t* __restrict__ xbf) {
    int i = (blockIdx.x * 256 + threadIdx.x) * 8;
    float4 a = *(const float4*)&x[i];
    float4 b = *(const float4*)&x[i + 4];
    uint4 r;
    r.x = (uint_t)f2bf(a.x) | ((uint_t)f2bf(a.y) << 16);
    r.y = (uint_t)f2bf(a.z) | ((uint_t)f2bf(a.w) << 16);
    r.z = (uint_t)f2bf(b.x) | ((uint_t)f2bf(b.y) << 16);
    r.w = (uint_t)f2bf(b.z) | ((uint_t)f2bf(b.w) << 16);
    *(uint4*)&xbf[i] = r;
}

// ------------------------------------------------------------------
// k2: per-row online softmax stats of S = G^T G via bf16 MFMA.
// Grid = 144 j-blocks x 8 q-splits = 1152 x 512 threads.
// Wave w: row-frag rf=w&3 (16 rows), q-pair qp=w>>2; A-frag invariant.
// ------------------------------------------------------------------
__global__ __launch_bounds__(512) void k2_stats(
        const ushort_t* __restrict__ Gbt, float* __restrict__ m_part,
        float* __restrict__ l_part) {
    __shared__ float mred[2][64], lred[2][64];
    int t = threadIdx.x;
    int w = t >> 6, l = t & 63;
    int l15 = l & 15, lg = l >> 4;
    int jb = blockIdx.x % 144, qs = blockIdx.x / 144;
    int j0 = jb * 64;
    int rf = w & 3, qp = w >> 2;
    bf16x8 aj = *(const bf16x8*)&Gbt[(j0 + rf * 16 + l15) * 32 + lg * 8];
    float m[4], lsum[4];
    #pragma unroll
    for (int r = 0; r < 4; ++r) { m[r] = -INFINITY; lsum[r] = 0.f; }
    int qbeg = qs * 1152;
    for (int tq = 0; tq < 18; ++tq) {
        int q0 = qbeg + tq * 64;
        bf16x8 b0 = *(const bf16x8*)&Gbt[(q0 + qp * 32 + l15) * 32 + lg * 8];
        bf16x8 b1 = *(const bf16x8*)&Gbt[(q0 + qp * 32 + 16 + l15) * 32 + lg * 8];
        f32x4 s0 = {0.f,0.f,0.f,0.f}, s1 = {0.f,0.f,0.f,0.f};
        s0 = __builtin_amdgcn_mfma_f32_16x16x32_bf16(aj, b0, s0, 0, 0, 0);
        s1 = __builtin_amdgcn_mfma_f32_16x16x32_bf16(aj, b1, s1, 0, 0, 0);
        #pragma unroll
        for (int r = 0; r < 4; ++r) {
            float tm = fmaxf(s0[r], s1[r]);
            float nm = fmaxf(m[r], tm);
            lsum[r] = lsum[r] * __expf(m[r] - nm)
                    + __expf(s0[r] - nm) + __expf(s1[r] - nm);
            m[r] = nm;
        }
    }
    #pragma unroll
    for (int off = 1; off < 16; off <<= 1) {
        #pragma unroll
        for (int r = 0; r < 4; ++r) {
            float mo = __shfl_xor(m[r], off);
            float lo = __shfl_xor(lsum[r], off);
            float nm = fmaxf(m[r], mo);
            lsum[r] = lsum[r] * __expf(m[r] - nm) + lo * __expf(mo - nm);
            m[r] = nm;
        }
    }
    if (l15 == 0) {
        #pragma unroll
        for (int r = 0; r < 4; ++r) {
            mred[qp][rf * 16 + lg * 4 + r] = m[r];
            lred[qp][rf * 16 + lg * 4 + r] = lsum[r];
        }
    }
    __syncthreads();
    if (t < 64) {
        float m0 = mred[0][t], m1 = mred[1][t];
        float l0 = lred[0][t], l1 = lred[1][t];
        float nm = fmaxf(m0, m1);
        float lv = l0 * __expf(m0 - nm) + l1 * __expf(m1 - nm);
        m_part[qs * HW + j0 + t] = nm;
        l_part[qs * HW + j0 + t] = lv;
    }
}

// merge 8 q-split partials -> mg, 1/l
__global__ __launch_bounds__(256) void k2b_merge(
        const float* __restrict__ m_part, const float* __restrict__ l_part,
        float* __restrict__ mg, float* __restrict__ rlg) {
    int j = blockIdx.x * 256 + threadIdx.x;
    float nm = -INFINITY;
    #pragma unroll
    for (int s = 0; s < 8; ++s) nm = fmaxf(nm, m_part[s * HW + j]);
    float lv = 0.f;
    #pragma unroll
    for (int s = 0; s < 8; ++s)
        lv += l_part[s * HW + j] * __expf(m_part[s * HW + j] - nm);
    mg[j] = nm;
    rlg[j] = 1.0f / lv;
}

__global__ __launch_bounds__(256) void kzero(float* __restrict__ Z) {
    int i = blockIdx.x * 256 + threadIdx.x;
    *(float4*)&Z[i * 4] = make_float4(0.f, 0.f, 0.f, 0.f);
}

// ------------------------------------------------------------------
// k3: Z[c,q] += sum_p xbf[c,p] * exp(S[p,q]-m_p)/l_p, bf16 MFMA.
// Grid = 144 q-blocks(64) x 8 p-splits = 1152 x 512 (8 waves).
// Per 32-p tile: phase A (1 MFMA/wave) -> Pbt[buf]; 1 barrier;
// phase B: A-frags DIRECT from global xbf, 8 MFMA/wave.
// ------------------------------------------------------------------
__global__ __launch_bounds__(512) void k3_pv(
        const ushort_t* __restrict__ xbf, const ushort_t* __restrict__ Gbt,
        const float* __restrict__ mg, const float* __restrict__ rlg,
        float* __restrict__ Z) {
    __shared__ ushort_t Pbt[2][64][40];    // [q][p], stride 80B (16B-aligned rows)
    int t = threadIdx.x;
    int w = t >> 6, l = t & 63;
    int l15 = l & 15, lg = l >> 4;
    int qb = blockIdx.x % 144, ps = blockIdx.x / 144;
    int q0 = qb * 64;
    int pf = w & 1, qf = w >> 1;
    // phase-A B-fragment (cols q, k=o contiguous): loop-invariant
    bf16x8 bqA = *(const bf16x8*)&Gbt[(q0 + qf * 16 + l15) * 32 + lg * 8];
    f32x4 acc[2][4];
    #pragma unroll
    for (int ci = 0; ci < 2; ++ci)
        #pragma unroll
        for (int n = 0; n < 4; ++n) acc[ci][n] = (f32x4){0.f,0.f,0.f,0.f};
    const ushort_t* xrow0 = &xbf[(w * 32 + l15) * HW + lg * 8];
    const ushort_t* xrow1 = xrow0 + 16 * HW;
    int p0beg = ps * 1152;

    for (int pt = 0; pt < 36; ++pt) {
        int p0 = p0beg + pt * 32;
        int buf = pt & 1;
        // ---- phase A: one 16x16 S quadrant per wave ----
        bf16x8 ap = *(const bf16x8*)&Gbt[(p0 + pf * 16 + l15) * 32 + lg * 8];
        f32x4 s = {0.f,0.f,0.f,0.f};
        s = __builtin_amdgcn_mfma_f32_16x16x32_bf16(ap, bqA, s, 0, 0, 0);
        int prow = p0 + pf * 16 + lg * 4;     // C row = p, col = q
        float4 m4 = *(const float4*)&mg[prow];
        float4 r4 = *(const float4*)&rlg[prow];
        uint_t w0 = (uint_t)f2bf(__expf(s[0] - m4.x) * r4.x)
                  | ((uint_t)f2bf(__expf(s[1] - m4.y) * r4.y) << 16);
        uint_t w1 = (uint_t)f2bf(__expf(s[2] - m4.z) * r4.z)
                  | ((uint_t)f2bf(__expf(s[3] - m4.w) * r4.w) << 16);
        uint2 pk; pk.x = w0; pk.y = w1;
        *(uint2*)&Pbt[buf][qf * 16 + l15][pf * 16 + lg * 4] = pk;
        __syncthreads();
        // ---- phase B: 64c x 64q per wave-tile, k=32 ----
        bf16x8 a0 = *(const bf16x8*)&xrow0[p0];
        bf16x8 a1 = *(const bf16x8*)&xrow1[p0];
        bf16x8 b0 = *(const bf16x8*)&Pbt[buf][l15][lg * 8];
        bf16x8 b1 = *(const bf16x8*)&Pbt[buf][16 + l15][lg * 8];
        bf16x8 b2 = *(const bf16x8*)&Pbt[buf][32 + l15][lg * 8];
        bf16x8 b3 = *(const bf16x8*)&Pbt[buf][48 + l15][lg * 8];
        acc[0][0] = __builtin_amdgcn_mfma_f32_16x16x32_bf16(a0, b0, acc[0][0], 0,0,0);
        acc[0][1] = __builtin_amdgcn_mfma_f32_16x16x32_bf16(a0, b1, acc[0][1], 0,0,0);
        acc[0][2] = __builtin_amdgcn_mfma_f32_16x16x32_bf16(a0, b2, acc[0][2], 0,0,0);
        acc[0][3] = __builtin_amdgcn_mfma_f32_16x16x32_bf16(a0, b3, acc[0][3], 0,0,0);
        acc[1][0] = __builtin_amdgcn_mfma_f32_16x16x32_bf16(a1, b0, acc[1][0], 0,0,0);
        acc[1][1] = __builtin_amdgcn_mfma_f32_16x16x32_bf16(a1, b1, acc[1][1], 0,0,0);
        acc[1][2] = __builtin_amdgcn_mfma_f32_16x16x32_bf16(a1, b2, acc[1][2], 0,0,0);
        acc[1][3] = __builtin_amdgcn_mfma_f32_16x16x32_bf16(a1, b3, acc[1][3], 0,0,0);
        // next iteration's phase A writes buf^1; barrier above protects reuse
    }
    int cbase = w * 32 + lg * 4;
    int qcol = q0 + l15;
    #pragma unroll
    for (int ci = 0; ci < 2; ++ci)
        #pragma unroll
        for (int n = 0; n < 4; ++n)
            #pragma unroll
            for (int r = 0; r < 4; ++r)
                atomicAdd(&Z[(cbase + ci * 16 + r) * HW + qcol + n * 16],
                          acc[ci][n][r]);
}

// ------------------------------------------------------------------
// k4: per-c row softmax of Z (9216) fused with final softmax over W.
// ------------------------------------------------------------------
__global__ __launch_bounds__(256) void k4_softmax(
        const float* __restrict__ x, float* __restrict__ ZO) {
    __shared__ float zrow[HW];
    __shared__ float red[4];
    int t = threadIdx.x, c = blockIdx.x;
    int lane = t & 63, wid = t >> 6;
    const float* Zr = &ZO[c * HW];
    float lm = -INFINITY;
    #pragma unroll
    for (int k = 0; k < 36; ++k) {
        float v = Zr[t + 256 * k];
        zrow[t + 256 * k] = v;
        lm = fmaxf(lm, v);
    }
    #pragma unroll
    for (int off = 32; off; off >>= 1) lm = fmaxf(lm, __shfl_xor(lm, off));
    if (lane == 0) red[wid] = lm;
    __syncthreads();
    float M = fmaxf(fmaxf(red[0], red[1]), fmaxf(red[2], red[3]));
    __syncthreads();
    float ls = 0.f;
    #pragma unroll
    for (int k = 0; k < 36; ++k) {
        int i = t + 256 * k;
        float e = __expf(zrow[i] - M);
        zrow[i] = e;
        ls += e;
    }
    #pragma unroll
    for (int off = 32; off; off >>= 1) ls += __shfl_xor(ls, off);
    if (lane == 0) red[wid] = ls;
    __syncthreads();
    float rS = 1.0f / (red[0] + red[1] + red[2] + red[3]);
    const float* xr = &x[c * HW];
    float* outr = &ZO[c * HW];
    for (int kk = 0; kk < 24; ++kk) {
        int h = wid + kk * 4;
        int base = h * 96;
        float v0 = fmaf(zrow[base + lane], rS, xr[base + lane]);
        float v1 = (lane < 32)
                 ? fmaf(zrow[base + 64 + lane], rS, xr[base + 64 + lane])
                 : -INFINITY;
        float mm = fmaxf(v0, v1);
        #pragma unroll
        for (int off = 32; off; off >>= 1) mm = fmaxf(mm, __shfl_xor(mm, off));
        float e0 = __expf(v0 - mm);
        float e1 = (lane < 32) ? __expf(v1 - mm) : 0.f;
        float ss = e0 + e1;
        #pragma unroll
        for (int off = 32; off; off >>= 1) ss += __shfl_xor(ss, off);
        float r = 1.0f / ss;
        outr[base + lane] = e0 * r;
        if (lane < 32) outr[base + 64 + lane] = e1 * r;
    }
}

extern "C" void kernel_launch(void* const* d_in, const int* in_sizes, int n_in,
                              void* d_out, int out_size, void* d_ws, size_t ws_size,
                              hipStream_t stream) {
    const float* x  = (const float*)d_in[0];   // [256,96,96]
    const float* wc = (const float*)d_in[1];   // [32,256]
    const float* bc = (const float*)d_in[2];   // [32]
    float* Z = (float*)d_out;                  // accum Z, then final out

    float* m_part = (float*)d_ws;              // 8*9216
    float* l_part = m_part + 8 * HW;           // 8*9216
    float* mg     = l_part + 8 * HW;           // 9216
    float* rlg    = mg + HW;                   // 9216
    ushort_t* xbf = (ushort_t*)(rlg + HW);     // 256*9216 bf16
    ushort_t* Gbt = xbf + 256 * HW;            // 9216*32 bf16

    k1_conv   <<<288,  256, 0, stream>>>(x, wc, bc, Gbt);
    k1b_cvt   <<<1152, 256, 0, stream>>>(x, xbf);
    k2_stats  <<<1152, 512, 0, stream>>>(Gbt, m_part, l_part);
    k2b_merge <<<36,   256, 0, stream>>>(m_part, l_part, mg, rlg);
    kzero     <<<2304, 256, 0, stream>>>(Z);
    k3_pv     <<<1152, 512, 0, stream>>>(xbf, Gbt, mg, rlg, Z);
    k4_softmax<<<256,  256, 0, stream>>>(x, Z);
}

// Round 4
// 205.524 us; speedup vs baseline: 8.7882x; 1.1347x over previous
//
#include <hip/hip_runtime.h>
#include <math.h>

#define HW 9216   // 96*96

typedef __attribute__((ext_vector_type(8))) short bf16x8;
typedef __attribute__((ext_vector_type(4))) float f32x4;
typedef unsigned short ushort_t;
typedef unsigned int uint_t;

__device__ __forceinline__ ushort_t f2bf(float f) {
    union { float f; uint_t u; } v; v.f = f;
    uint_t u = v.u + 0x7FFF + ((v.u >> 16) & 1);   // RNE
    return (ushort_t)(u >> 16);
}

// raw barrier: LDS-visibility only, no vmcnt drain (prefetches stay in flight)
#define BAR() do { asm volatile("s_waitcnt lgkmcnt(0)" ::: "memory"); \
                   __builtin_amdgcn_s_barrier(); } while (0)

// ------------------------------------------------------------------
// k1: 1x1 conv -> Gbt[p][o] bf16 (p = w*96+h permuted, o contiguous).
// ------------------------------------------------------------------
__global__ __launch_bounds__(256) void k1_conv(
        const float* __restrict__ x, const float* __restrict__ wc,
        const float* __restrict__ bc, ushort_t* __restrict__ Gbt) {
    __shared__ float wt[256][32];          // [c][o] 32KB
    __shared__ float red[8][32][33];       // [cg][px][o] padded
    int t = threadIdx.x;
    for (int i = t; i < 256 * 32; i += 256) {
        int o = i >> 8, c = i & 255;       // wc is [o][c]
        wt[c][o] = wc[i];
    }
    __syncthreads();
    int px = t & 31, cg = t >> 5;
    int n = blockIdx.x * 32 + px;
    float acc[32];
    #pragma unroll
    for (int o = 0; o < 32; ++o) acc[o] = 0.f;
    int c0 = cg * 32;
    for (int cc = 0; cc < 32; ++cc) {
        int c = c0 + cc;
        float xv = x[c * HW + n];
        #pragma unroll
        for (int o4 = 0; o4 < 8; ++o4) {
            float4 wv = *(const float4*)&wt[c][o4 * 4];
            acc[o4*4+0] = fmaf(wv.x, xv, acc[o4*4+0]);
            acc[o4*4+1] = fmaf(wv.y, xv, acc[o4*4+1]);
            acc[o4*4+2] = fmaf(wv.z, xv, acc[o4*4+2]);
            acc[o4*4+3] = fmaf(wv.w, xv, acc[o4*4+3]);
        }
    }
    #pragma unroll
    for (int o = 0; o < 32; ++o) red[cg][px][o] = acc[o];
    __syncthreads();
    int px2 = t >> 3, o2 = (t & 7) * 4;
    float s[4] = {0.f, 0.f, 0.f, 0.f};
    #pragma unroll
    for (int g = 0; g < 8; ++g) {
        s[0] += red[g][px2][o2 + 0];
        s[1] += red[g][px2][o2 + 1];
        s[2] += red[g][px2][o2 + 2];
        s[3] += red[g][px2][o2 + 3];
    }
    int n2 = blockIdx.x * 32 + px2;
    int h = n2 / 96, w = n2 % 96;
    int p = w * 96 + h;
    uint2 pk;
    pk.x = (uint_t)f2bf(s[0] + bc[o2+0]) | ((uint_t)f2bf(s[1] + bc[o2+1]) << 16);
    pk.y = (uint_t)f2bf(s[2] + bc[o2+2]) | ((uint_t)f2bf(s[3] + bc[o2+3]) << 16);
    *(uint2*)&Gbt[p * 32 + o2] = pk;
}

// ------------------------------------------------------------------
// k1b: x (f32, [c][j]) -> xtile bf16, tiled [jt][c][32] so that k3's
// A-fragment loads are dense (16 consecutive 64B rows per wave).
// ------------------------------------------------------------------
__global__ __launch_bounds__(256) void k1b_tile(
        const float* __restrict__ x, ushort_t* __restrict__ xtile) {
    int jt = blockIdx.x;                   // 0..287
    int c = threadIdx.x;                   // 0..255
    const float* src = &x[c * HW + jt * 32];
    ushort_t* dst = &xtile[(jt * 256 + c) * 32];
    #pragma unroll
    for (int k = 0; k < 4; ++k) {
        float4 a = *(const float4*)&src[k * 8];
        float4 b = *(const float4*)&src[k * 8 + 4];
        uint4 r;
        r.x = (uint_t)f2bf(a.x) | ((uint_t)f2bf(a.y) << 16);
        r.y = (uint_t)f2bf(a.z) | ((uint_t)f2bf(a.w) << 16);
        r.z = (uint_t)f2bf(b.x) | ((uint_t)f2bf(b.y) << 16);
        r.w = (uint_t)f2bf(b.z) | ((uint_t)f2bf(b.w) << 16);
        *(uint4*)&dst[k * 8] = r;
    }
}

// ------------------------------------------------------------------
// k2: per-row online softmax stats of S = G^T G via bf16 MFMA.
// ------------------------------------------------------------------
__global__ __launch_bounds__(512) void k2_stats(
        const ushort_t* __restrict__ Gbt, float* __restrict__ m_part,
        float* __restrict__ l_part) {
    __shared__ float mred[2][64], lred[2][64];
    int t = threadIdx.x;
    int w = t >> 6, l = t & 63;
    int l15 = l & 15, lg = l >> 4;
    int jb = blockIdx.x % 144, qs = blockIdx.x / 144;
    int j0 = jb * 64;
    int rf = w & 3, qp = w >> 2;
    bf16x8 aj = *(const bf16x8*)&Gbt[(j0 + rf * 16 + l15) * 32 + lg * 8];
    float m[4], lsum[4];
    #pragma unroll
    for (int r = 0; r < 4; ++r) { m[r] = -INFINITY; lsum[r] = 0.f; }
    int qbeg = qs * 1152;
    for (int tq = 0; tq < 18; ++tq) {
        int q0 = qbeg + tq * 64;
        bf16x8 b0 = *(const bf16x8*)&Gbt[(q0 + qp * 32 + l15) * 32 + lg * 8];
        bf16x8 b1 = *(const bf16x8*)&Gbt[(q0 + qp * 32 + 16 + l15) * 32 + lg * 8];
        f32x4 s0 = {0.f,0.f,0.f,0.f}, s1 = {0.f,0.f,0.f,0.f};
        s0 = __builtin_amdgcn_mfma_f32_16x16x32_bf16(aj, b0, s0, 0, 0, 0);
        s1 = __builtin_amdgcn_mfma_f32_16x16x32_bf16(aj, b1, s1, 0, 0, 0);
        #pragma unroll
        for (int r = 0; r < 4; ++r) {
            float tm = fmaxf(s0[r], s1[r]);
            float nm = fmaxf(m[r], tm);
            lsum[r] = lsum[r] * __expf(m[r] - nm)
                    + __expf(s0[r] - nm) + __expf(s1[r] - nm);
            m[r] = nm;
        }
    }
    #pragma unroll
    for (int off = 1; off < 16; off <<= 1) {
        #pragma unroll
        for (int r = 0; r < 4; ++r) {
            float mo = __shfl_xor(m[r], off);
            float lo = __shfl_xor(lsum[r], off);
            float nm = fmaxf(m[r], mo);
            lsum[r] = lsum[r] * __expf(m[r] - nm) + lo * __expf(mo - nm);
            m[r] = nm;
        }
    }
    if (l15 == 0) {
        #pragma unroll
        for (int r = 0; r < 4; ++r) {
            mred[qp][rf * 16 + lg * 4 + r] = m[r];
            lred[qp][rf * 16 + lg * 4 + r] = lsum[r];
        }
    }
    __syncthreads();
    if (t < 64) {
        float m0 = mred[0][t], m1 = mred[1][t];
        float l0 = lred[0][t], l1 = lred[1][t];
        float nm = fmaxf(m0, m1);
        float lv = l0 * __expf(m0 - nm) + l1 * __expf(m1 - nm);
        m_part[qs * HW + j0 + t] = nm;
        l_part[qs * HW + j0 + t] = lv;
    }
}

__global__ __launch_bounds__(256) void k2b_merge(
        const float* __restrict__ m_part, const float* __restrict__ l_part,
        float* __restrict__ mg, float* __restrict__ rlg) {
    int j = blockIdx.x * 256 + threadIdx.x;
    float nm = -INFINITY;
    #pragma unroll
    for (int s = 0; s < 8; ++s) nm = fmaxf(nm, m_part[s * HW + j]);
    float lv = 0.f;
    #pragma unroll
    for (int s = 0; s < 8; ++s)
        lv += l_part[s * HW + j] * __expf(m_part[s * HW + j] - nm);
    mg[j] = nm;
    rlg[j] = 1.0f / lv;
}

__global__ __launch_bounds__(256) void kzero(float* __restrict__ Z) {
    int i = blockIdx.x * 256 + threadIdx.x;
    *(float4*)&Z[i * 4] = make_float4(0.f, 0.f, 0.f, 0.f);
}

// ------------------------------------------------------------------
// k3: Z[c,q] += sum_p xtile[c,p] * exp(S[p,q]-m_p)/l_p, bf16 MFMA.
// Grid = 144 q-blocks(64) x 8 p-splits = 1152 x 512 (8 waves).
// Per 32-p tile: issue a-loads early; phase A (1 MFMA/wave) -> Pbt;
// raw barrier (no vmcnt drain); phase B 8 MFMA/wave with in-flight a.
// ------------------------------------------------------------------
__global__ __launch_bounds__(512) void k3_pv(
        const ushort_t* __restrict__ xtile, const ushort_t* __restrict__ Gbt,
        const float* __restrict__ mg, const float* __restrict__ rlg,
        float* __restrict__ Z) {
    __shared__ ushort_t Pbt[2][64][40];    // [q][p], 80B rows (2-way = free)
    int t = threadIdx.x;
    int w = t >> 6, l = t & 63;
    int l15 = l & 15, lg = l >> 4;
    int qb = blockIdx.x % 144, ps = blockIdx.x / 144;
    int q0 = qb * 64;
    int pf = w & 1, qf = w >> 1;
    // phase-A B-fragment (cols q, k=o contiguous): loop-invariant
    bf16x8 bqA = *(const bf16x8*)&Gbt[(q0 + qf * 16 + l15) * 32 + lg * 8];
    f32x4 acc[2][4];
    #pragma unroll
    for (int ci = 0; ci < 2; ++ci)
        #pragma unroll
        for (int n = 0; n < 4; ++n) acc[ci][n] = (f32x4){0.f,0.f,0.f,0.f};
    // dense A-frag base: row = w*32 (+16 for a1) + l15, 64B rows
    const ushort_t* xt0 = &xtile[(w * 32 + l15) * 32 + lg * 8];
    const ushort_t* xt1 = xt0 + 16 * 32;
    int tile0 = ps * 36;
    int p0beg = ps * 1152;
    // preload phase-A fragment for tile 0
    bf16x8 ap_c = *(const bf16x8*)&Gbt[(p0beg + pf * 16 + l15) * 32 + lg * 8];

    for (int pt = 0; pt < 36; ++pt) {
        int p0 = p0beg + pt * 32;
        int buf = pt & 1;
        size_t toff = (size_t)(tile0 + pt) * 8192;
        // issue this tile's A-operand loads early (used after barrier)
        bf16x8 a0 = *(const bf16x8*)&xt0[toff];
        bf16x8 a1 = *(const bf16x8*)&xt1[toff];
        int prow = p0 + pf * 16 + lg * 4;
        float4 m4 = *(const float4*)&mg[prow];
        float4 r4 = *(const float4*)&rlg[prow];
        // ---- phase A: one 16x16 S quadrant per wave ----
        f32x4 s = {0.f,0.f,0.f,0.f};
        s = __builtin_amdgcn_mfma_f32_16x16x32_bf16(ap_c, bqA, s, 0, 0, 0);
        // prefetch next tile's phase-A fragment (clamped on last iter)
        int pnext = (pt == 35) ? p0 : p0 + 32;
        ap_c = *(const bf16x8*)&Gbt[(pnext + pf * 16 + l15) * 32 + lg * 8];
        uint_t w0 = (uint_t)f2bf(__expf(s[0] - m4.x) * r4.x)
                  | ((uint_t)f2bf(__expf(s[1] - m4.y) * r4.y) << 16);
        uint_t w1 = (uint_t)f2bf(__expf(s[2] - m4.z) * r4.z)
                  | ((uint_t)f2bf(__expf(s[3] - m4.w) * r4.w) << 16);
        uint2 pk; pk.x = w0; pk.y = w1;
        *(uint2*)&Pbt[buf][qf * 16 + l15][pf * 16 + lg * 4] = pk;
        BAR();                             // LDS visible; vmem stays in flight
        // ---- phase B: 32c x 64q per wave, k=32 ----
        bf16x8 b0 = *(const bf16x8*)&Pbt[buf][l15][lg * 8];
        bf16x8 b1 = *(const bf16x8*)&Pbt[buf][16 + l15][lg * 8];
        bf16x8 b2 = *(const bf16x8*)&Pbt[buf][32 + l15][lg * 8];
        bf16x8 b3 = *(const bf16x8*)&Pbt[buf][48 + l15][lg * 8];
        acc[0][0] = __builtin_amdgcn_mfma_f32_16x16x32_bf16(a0, b0, acc[0][0], 0,0,0);
        acc[0][1] = __builtin_amdgcn_mfma_f32_16x16x32_bf16(a0, b1, acc[0][1], 0,0,0);
        acc[0][2] = __builtin_amdgcn_mfma_f32_16x16x32_bf16(a0, b2, acc[0][2], 0,0,0);
        acc[0][3] = __builtin_amdgcn_mfma_f32_16x16x32_bf16(a0, b3, acc[0][3], 0,0,0);
        acc[1][0] = __builtin_amdgcn_mfma_f32_16x16x32_bf16(a1, b0, acc[1][0], 0,0,0);
        acc[1][1] = __builtin_amdgcn_mfma_f32_16x16x32_bf16(a1, b1, acc[1][1], 0,0,0);
        acc[1][2] = __builtin_amdgcn_mfma_f32_16x16x32_bf16(a1, b2, acc[1][2], 0,0,0);
        acc[1][3] = __builtin_amdgcn_mfma_f32_16x16x32_bf16(a1, b3, acc[1][3], 0,0,0);
    }
    int cbase = w * 32 + lg * 4;
    int qcol = q0 + l15;
    #pragma unroll
    for (int ci = 0; ci < 2; ++ci)
        #pragma unroll
        for (int n = 0; n < 4; ++n)
            #pragma unroll
            for (int r = 0; r < 4; ++r)
                atomicAdd(&Z[(cbase + ci * 16 + r) * HW + qcol + n * 16],
                          acc[ci][n][r]);
}

// ------------------------------------------------------------------
// k4: per-c row softmax of Z (9216) fused with final softmax over W.
// ------------------------------------------------------------------
__global__ __launch_bounds__(256) void k4_softmax(
        const float* __restrict__ x, float* __restrict__ ZO) {
    __shared__ float zrow[HW];
    __shared__ float red[4];
    int t = threadIdx.x, c = blockIdx.x;
    int lane = t & 63, wid = t >> 6;
    const float* Zr = &ZO[c * HW];
    float lm = -INFINITY;
    #pragma unroll
    for (int k = 0; k < 36; ++k) {
        float v = Zr[t + 256 * k];
        zrow[t + 256 * k] = v;
        lm = fmaxf(lm, v);
    }
    #pragma unroll
    for (int off = 32; off; off >>= 1) lm = fmaxf(lm, __shfl_xor(lm, off));
    if (lane == 0) red[wid] = lm;
    __syncthreads();
    float M = fmaxf(fmaxf(red[0], red[1]), fmaxf(red[2], red[3]));
    __syncthreads();
    float ls = 0.f;
    #pragma unroll
    for (int k = 0; k < 36; ++k) {
        int i = t + 256 * k;
        float e = __expf(zrow[i] - M);
        zrow[i] = e;
        ls += e;
    }
    #pragma unroll
    for (int off = 32; off; off >>= 1) ls += __shfl_xor(ls, off);
    if (lane == 0) red[wid] = ls;
    __syncthreads();
    float rS = 1.0f / (red[0] + red[1] + red[2] + red[3]);
    const float* xr = &x[c * HW];
    float* outr = &ZO[c * HW];
    for (int kk = 0; kk < 24; ++kk) {
        int h = wid + kk * 4;
        int base = h * 96;
        float v0 = fmaf(zrow[base + lane], rS, xr[base + lane]);
        float v1 = (lane < 32)
                 ? fmaf(zrow[base + 64 + lane], rS, xr[base + 64 + lane])
                 : -INFINITY;
        float mm = fmaxf(v0, v1);
        #pragma unroll
        for (int off = 32; off; off >>= 1) mm = fmaxf(mm, __shfl_xor(mm, off));
        float e0 = __expf(v0 - mm);
        float e1 = (lane < 32) ? __expf(v1 - mm) : 0.f;
        float ss = e0 + e1;
        #pragma unroll
        for (int off = 32; off; off >>= 1) ss += __shfl_xor(ss, off);
        float r = 1.0f / ss;
        outr[base + lane] = e0 * r;
        if (lane < 32) outr[base + 64 + lane] = e1 * r;
    }
}

extern "C" void kernel_launch(void* const* d_in, const int* in_sizes, int n_in,
                              void* d_out, int out_size, void* d_ws, size_t ws_size,
                              hipStream_t stream) {
    const float* x  = (const float*)d_in[0];   // [256,96,96]
    const float* wc = (const float*)d_in[1];   // [32,256]
    const float* bc = (const float*)d_in[2];   // [32]
    float* Z = (float*)d_out;                  // accum Z, then final out

    float* m_part = (float*)d_ws;              // 8*9216
    float* l_part = m_part + 8 * HW;           // 8*9216
    float* mg     = l_part + 8 * HW;           // 9216
    float* rlg    = mg + HW;                   // 9216
    ushort_t* xtile = (ushort_t*)(rlg + HW);   // 288*256*32 bf16 (tiled x)
    ushort_t* Gbt   = xtile + 256 * HW;        // 9216*32 bf16

    k1_conv   <<<288,  256, 0, stream>>>(x, wc, bc, Gbt);
    k1b_tile  <<<288,  256, 0, stream>>>(x, xtile);
    k2_stats  <<<1152, 512, 0, stream>>>(Gbt, m_part, l_part);
    k2b_merge <<<36,   256, 0, stream>>>(m_part, l_part, mg, rlg);
    kzero     <<<2304, 256, 0, stream>>>(Z);
    k3_pv     <<<1152, 512, 0, stream>>>(xtile, Gbt, mg, rlg, Z);
    k4_softmax<<<256,  256, 0, stream>>>(x, Z);
}